// Round 1
// baseline (508.591 us; speedup 1.0000x reference)
//
#include <hip/hip_runtime.h>

// ---------------------------------------------------------------------------
// CISSVAE forward on gfx950.
// Strategy: cluster-sort rows (padded to 128-row tiles), run whole net in
// permuted order with bf16 MFMA GEMMs (m97 structure: 128x128 tile, BK=32,
// global_load_lds width-16, 16x16x32_bf16), scatter outputs at the end.
// ---------------------------------------------------------------------------

#define DEVI __device__ __forceinline__

constexpr int B_    = 8192;
constexpr int DIN   = 2048;
constexpr int H0_   = 1024;
constexpr int H1_   = 512;
constexpr int LAT_  = 128;
constexpr int NC    = 8;

constexpr int BM = 128, BN = 128, BK = 32;
constexpr int TCAP   = 72;            // sum ceil(cnt_c/128) <= 64 + 7
constexpr int BP_CAP = TCAP * BM;     // 9216 padded rows

// meta int indices (in ws)
#define MI_CURSOR 0   // 8 ints: scatter cursors (start at padded seg base)
#define MI_NTILES 8
#define MI_TILEC  16  // 72 ints: tile -> cluster

typedef __attribute__((ext_vector_type(8))) short bf16x8;
typedef __attribute__((ext_vector_type(4))) float f32x4;
typedef const __attribute__((address_space(1))) unsigned int* gas_uint_ptr;
typedef __attribute__((address_space(3))) unsigned int* las_uint_ptr;

DEVI unsigned short f2bf(float f) {      // RNE float -> bf16 bits
  union { float f; unsigned u; } a; a.f = f;
  unsigned r = a.u + 0x7fffu + ((a.u >> 16) & 1u);
  return (unsigned short)(r >> 16);
}

DEVI void gll16(const unsigned short* g, unsigned short* l) {
  __builtin_amdgcn_global_load_lds((gas_uint_ptr)g, (las_uint_ptr)l, 16, 0, 0);
}

// ---------------- workspace layout ----------------
constexpr size_t AL256(size_t x) { return (x + 255) & ~(size_t)255; }
constexpr size_t OFF_META = 0;                                       // 512 B
constexpr size_t OFF_PERM = 512;                                     // BP_CAP ints
constexpr size_t OFF_XG   = AL256(OFF_PERM + (size_t)BP_CAP * 4);    // u16 [BP_CAP][DIN]   (reused as d1 [BP_CAP][H0])
constexpr size_t OFF_H0   = AL256(OFF_XG  + (size_t)BP_CAP * DIN * 2); // u16 [BP_CAP][H0]  (reused as d0 [BP_CAP][H1])
constexpr size_t OFF_H1   = AL256(OFF_H0  + (size_t)BP_CAP * H0_ * 2); // u16 [BP_CAP][H1]  (reused as z [BP_CAP][LAT])
constexpr size_t OFF_MLP  = AL256(OFF_H1  + (size_t)BP_CAP * H1_ * 2); // f32 [BP_CAP][256] mu|logvar
constexpr size_t OFF_BML  = AL256(OFF_MLP + (size_t)BP_CAP * 256 * 4); // f32 [256]
constexpr size_t OFF_WT0  = AL256(OFF_BML + 256 * 4);                  // u16 [NC][H0][DIN]
constexpr size_t OFF_WT1  = AL256(OFF_WT0 + (size_t)NC * DIN * H0_ * 2); // u16 [H1][H0]
constexpr size_t OFF_WML  = AL256(OFF_WT1 + (size_t)H0_ * H1_ * 2);      // u16 [256][H1]
constexpr size_t OFF_WD0  = AL256(OFF_WML + (size_t)256 * H1_ * 2);      // u16 [H1][LAT]
constexpr size_t OFF_WD1  = AL256(OFF_WD0 + (size_t)LAT_ * H1_ * 2);     // u16 [NC][H0][H1]
constexpr size_t OFF_WOUT = AL256(OFF_WD1 + (size_t)NC * H1_ * H0_ * 2); // u16 [DIN][H0]

// ---------------- setup kernels ----------------
__global__ void setup_a(const int* __restrict__ labels, int* __restrict__ meta,
                        int* __restrict__ perm) {
  __shared__ int cnt[NC];
  int t = threadIdx.x;
  if (t < NC) cnt[t] = 0;
  __syncthreads();
  for (int i = t; i < B_; i += 256) atomicAdd(&cnt[labels[i]], 1);
  for (int i = t; i < BP_CAP; i += 256) perm[i] = -1;
  __syncthreads();
  if (t == 0) {
    int off = 0, nt = 0;
    for (int c = 0; c < NC; ++c) {
      meta[MI_CURSOR + c] = off;
      int k = (cnt[c] + BM - 1) >> 7;
      for (int j = 0; j < k; ++j) meta[MI_TILEC + nt + j] = c;
      nt += k;
      off += k << 7;
    }
    meta[MI_NTILES] = nt;
  }
}

__global__ void setup_b(const int* __restrict__ labels, int* __restrict__ meta,
                        int* __restrict__ perm) {
  int i = blockIdx.x * 256 + threadIdx.x;
  if (i < B_) {
    int pos = atomicAdd(&meta[MI_CURSOR + labels[i]], 1);
    perm[pos] = i;
  }
}

__global__ void concat_bias(const float* __restrict__ a, const float* __restrict__ b,
                            float* __restrict__ o) {
  int j = threadIdx.x;
  o[j] = (j < 128) ? a[j] : b[j - 128];
}

// fp32 [batch][K][N] -> bf16 [batch][N][K]
__global__ void convert_transpose(const float* __restrict__ src, unsigned short* __restrict__ dst,
                                  int K, int N) {
  __shared__ float t[32][33];
  const float* s = src + (size_t)blockIdx.z * K * N;
  unsigned short* d = dst + (size_t)blockIdx.z * K * N;
  int n0 = blockIdx.x * 32, k0 = blockIdx.y * 32;
  for (int i = threadIdx.y; i < 32; i += 8)
    t[i][threadIdx.x] = s[(size_t)(k0 + i) * N + n0 + threadIdx.x];
  __syncthreads();
  for (int i = threadIdx.y; i < 32; i += 8)
    d[(size_t)(n0 + i) * K + k0 + threadIdx.x] = f2bf(t[threadIdx.x][i]);
}

// gather + fp32->bf16 rows of x into permuted layout (zeros for padding rows)
__global__ void gather_x_kernel(const float* __restrict__ x, const int* __restrict__ perm,
                                unsigned short* __restrict__ xg) {
  int p = blockIdx.x;
  int c4 = blockIdx.y * 256 + threadIdx.x;   // 0..511 float4 per row
  int src = perm[p];
  float4 v = make_float4(0.f, 0.f, 0.f, 0.f);
  if (src >= 0) v = ((const float4*)(x + (size_t)src * DIN))[c4];
  ushort4 o;
  o.x = f2bf(v.x); o.y = f2bf(v.y); o.z = f2bf(v.z); o.w = f2bf(v.w);
  ((ushort4*)(xg + (size_t)p * DIN))[c4] = o;
}

// z = mu + eps*exp(0.5*logvar); scatter mu/logvar to output
__global__ void z_kernel(const float* __restrict__ mlp, const float* __restrict__ eps,
                         const int* __restrict__ perm, unsigned short* __restrict__ z,
                         float* __restrict__ out_mu, float* __restrict__ out_lv) {
  int p = blockIdx.x, j = threadIdx.x;
  int src = perm[p];
  float zz = 0.f;
  if (src >= 0) {
    float m = mlp[(size_t)p * 256 + j];
    float l = mlp[(size_t)p * 256 + 128 + j];
    zz = m + eps[(size_t)src * LAT_ + j] * expf(0.5f * l);
    out_mu[(size_t)src * LAT_ + j] = m;
    out_lv[(size_t)src * LAT_ + j] = l;
  }
  z[(size_t)p * LAT_ + j] = f2bf(zz);
}

// ---------------- the GEMM engine (m97 structure) ----------------
// C[M,N] = A[M,K] @ Bt[N,K]^T, A/Bt bf16, acc fp32; +bias, optional relu.
// OUT_MODE: 0 = bf16 buffer [BP_CAP][N], 1 = f32 buffer [BP_CAP][N],
//           2 = f32 scatter rows via perm, ld = ldc
template <int OUT_MODE, bool RELU, bool PCW, bool PCB>
__global__ __launch_bounds__(256, 2)
void gemm_kernel(const unsigned short* __restrict__ A,
                 const unsigned short* __restrict__ Bt,
                 const float* __restrict__ bias,
                 void* __restrict__ Cout,
                 const int* __restrict__ meta,
                 const int* __restrict__ perm,
                 int K, int N, int ldc) {
  const int ntiles = meta[MI_NTILES];
  const int tm = blockIdx.x;
  if (tm >= ntiles) return;
  const int tn = blockIdx.y;

  int cluster = 0;
  if (PCW || PCB) cluster = meta[MI_TILEC + tm];
  const unsigned short* Bp = Bt + (PCW ? (size_t)cluster * (size_t)N * K : 0);
  const float* bb = bias + (PCB ? (size_t)cluster * N : 0);

  __shared__ alignas(16) unsigned short As[BM][BK];
  __shared__ alignas(16) unsigned short Bs[BN][BK];

  const int tid  = threadIdx.x;
  const int w    = tid >> 6, lane = tid & 63;
  const int fr   = lane & 15, quad = lane >> 4;
  const int wm   = (w >> 1) * 64, wn = (w & 1) * 64;

  // staging: 512 16B-chunks per tile; chunk = (w*2+it)*64 + lane
  const int c0 = (w * 2 + 0) * 64 + lane;
  const int c1 = (w * 2 + 1) * 64 + lane;
  const size_t aoff0 = (size_t)(tm * BM + (c0 >> 2)) * K + (c0 & 3) * 8;
  const size_t aoff1 = (size_t)(tm * BM + (c1 >> 2)) * K + (c1 & 3) * 8;
  const size_t boff0 = (size_t)(tn * BN + (c0 >> 2)) * K + (c0 & 3) * 8;
  const size_t boff1 = (size_t)(tn * BN + (c1 >> 2)) * K + (c1 & 3) * 8;
  unsigned short* lA0 = &As[0][0] + (w * 2 + 0) * 512;
  unsigned short* lA1 = &As[0][0] + (w * 2 + 1) * 512;
  unsigned short* lB0 = &Bs[0][0] + (w * 2 + 0) * 512;
  unsigned short* lB1 = &Bs[0][0] + (w * 2 + 1) * 512;

  f32x4 acc[4][4] = {};

  for (int k0 = 0; k0 < K; k0 += BK) {
    gll16(A  + aoff0 + k0, lA0);
    gll16(A  + aoff1 + k0, lA1);
    gll16(Bp + boff0 + k0, lB0);
    gll16(Bp + boff1 + k0, lB1);
    __syncthreads();  // drains vmcnt, LDS tile ready

    bf16x8 af[4], bf[4];
#pragma unroll
    for (int i = 0; i < 4; ++i) af[i] = *(const bf16x8*)&As[wm + i * 16 + fr][quad * 8];
#pragma unroll
    for (int i = 0; i < 4; ++i) bf[i] = *(const bf16x8*)&Bs[wn + i * 16 + fr][quad * 8];
#pragma unroll
    for (int mi = 0; mi < 4; ++mi)
#pragma unroll
      for (int ni = 0; ni < 4; ++ni)
        acc[mi][ni] = __builtin_amdgcn_mfma_f32_16x16x32_bf16(af[mi], bf[ni], acc[mi][ni], 0, 0, 0);
    __syncthreads();  // all waves done reading LDS before restage
  }

  // epilogue: D row = wm + mi*16 + quad*4 + r (M), col = wn + ni*16 + fr (N)
  float bv[4];
#pragma unroll
  for (int ni = 0; ni < 4; ++ni) bv[ni] = bb[tn * BN + wn + ni * 16 + fr];

#pragma unroll
  for (int mi = 0; mi < 4; ++mi) {
#pragma unroll
    for (int r = 0; r < 4; ++r) {
      int m = tm * BM + wm + mi * 16 + quad * 4 + r;
      int orow = m;
      if (OUT_MODE == 2) orow = perm[m];
#pragma unroll
      for (int ni = 0; ni < 4; ++ni) {
        int n = tn * BN + wn + ni * 16 + fr;
        float v = acc[mi][ni][r] + bv[ni];
        if (RELU) v = fmaxf(v, 0.f);
        if (OUT_MODE == 0) {
          ((unsigned short*)Cout)[(size_t)m * N + n] = f2bf(v);
        } else if (OUT_MODE == 1) {
          ((float*)Cout)[(size_t)m * N + n] = v;
        } else {
          if (orow >= 0) ((float*)Cout)[(size_t)orow * ldc + n] = v;
        }
      }
    }
  }
}

// ---------------- launch ----------------
extern "C" void kernel_launch(void* const* d_in, const int* in_sizes, int n_in,
                              void* d_out, int out_size, void* d_ws, size_t ws_size,
                              hipStream_t stream) {
  const float* x        = (const float*)d_in[0];
  const int*   labels   = (const int*)d_in[1];
  const float* eps      = (const float*)d_in[2];
  const float* W_enc0   = (const float*)d_in[3];
  const float* b_enc0   = (const float*)d_in[4];
  const float* W_enc1   = (const float*)d_in[5];
  const float* b_enc1   = (const float*)d_in[6];
  const float* W_mu     = (const float*)d_in[7];
  const float* b_mu     = (const float*)d_in[8];
  const float* W_logvar = (const float*)d_in[9];
  const float* b_logvar = (const float*)d_in[10];
  const float* W_dec0   = (const float*)d_in[11];
  const float* b_dec0   = (const float*)d_in[12];
  const float* W_dec1   = (const float*)d_in[13];
  const float* b_dec1   = (const float*)d_in[14];
  const float* W_out    = (const float*)d_in[15];
  const float* b_out    = (const float*)d_in[16];

  float* out_recon = (float*)d_out;
  float* out_mu    = out_recon + (size_t)B_ * DIN;
  float* out_lv    = out_mu + (size_t)B_ * LAT_;

  char* ws = (char*)d_ws;
  int* meta            = (int*)(ws + OFF_META);
  int* perm            = (int*)(ws + OFF_PERM);
  unsigned short* xg   = (unsigned short*)(ws + OFF_XG);
  unsigned short* h0   = (unsigned short*)(ws + OFF_H0);
  unsigned short* h1   = (unsigned short*)(ws + OFF_H1);
  float* mlp           = (float*)(ws + OFF_MLP);
  float* b_ml          = (float*)(ws + OFF_BML);
  unsigned short* Wt0  = (unsigned short*)(ws + OFF_WT0);
  unsigned short* Wt1  = (unsigned short*)(ws + OFF_WT1);
  unsigned short* Wml  = (unsigned short*)(ws + OFF_WML);
  unsigned short* Wd0  = (unsigned short*)(ws + OFF_WD0);
  unsigned short* Wd1  = (unsigned short*)(ws + OFF_WD1);
  unsigned short* Wout = (unsigned short*)(ws + OFF_WOUT);
  // buffer reuse (lifetimes disjoint):
  unsigned short* d1 = xg;   // [BP_CAP][H0]
  unsigned short* d0 = h0;   // [BP_CAP][H1]
  unsigned short* z  = h1;   // [BP_CAP][LAT]

  dim3 cb(32, 8);

  setup_a<<<1, 256, 0, stream>>>(labels, meta, perm);
  setup_b<<<(B_ + 255) / 256, 256, 0, stream>>>(labels, meta, perm);
  concat_bias<<<1, 256, 0, stream>>>(b_mu, b_logvar, b_ml);

  convert_transpose<<<dim3(H0_ / 32, DIN / 32, NC), cb, 0, stream>>>(W_enc0, Wt0, DIN, H0_);
  convert_transpose<<<dim3(H1_ / 32, H0_ / 32, 1), cb, 0, stream>>>(W_enc1, Wt1, H0_, H1_);
  convert_transpose<<<dim3(LAT_ / 32, H1_ / 32, 1), cb, 0, stream>>>(W_mu, Wml, H1_, LAT_);
  convert_transpose<<<dim3(LAT_ / 32, H1_ / 32, 1), cb, 0, stream>>>(W_logvar, Wml + (size_t)LAT_ * H1_, H1_, LAT_);
  convert_transpose<<<dim3(H1_ / 32, LAT_ / 32, 1), cb, 0, stream>>>(W_dec0, Wd0, LAT_, H1_);
  convert_transpose<<<dim3(H0_ / 32, H1_ / 32, NC), cb, 0, stream>>>(W_dec1, Wd1, H1_, H0_);
  convert_transpose<<<dim3(DIN / 32, H0_ / 32, 1), cb, 0, stream>>>(W_out, Wout, H0_, DIN);

  gather_x_kernel<<<dim3(BP_CAP, DIN / (256 * 4)), 256, 0, stream>>>(x, perm, xg);

  // enc0: [Bp,2048] @ Wt0[c][1024][2048] -> h0, relu
  gemm_kernel<0, true, true, true><<<dim3(TCAP, H0_ / BN), 256, 0, stream>>>(
      xg, Wt0, b_enc0, h0, meta, perm, DIN, H0_, 0);
  // enc1: [Bp,1024] @ Wt1[512][1024] -> h1, relu
  gemm_kernel<0, true, false, false><<<dim3(TCAP, H1_ / BN), 256, 0, stream>>>(
      h0, Wt1, b_enc1, h1, meta, perm, H0_, H1_, 0);
  // mu|logvar: [Bp,512] @ Wml[256][512] -> mlp (fp32)
  gemm_kernel<1, false, false, false><<<dim3(TCAP, 256 / BN), 256, 0, stream>>>(
      h1, Wml, b_ml, mlp, meta, perm, H1_, 256, 0);
  // reparameterize + scatter mu/logvar
  z_kernel<<<BP_CAP, 128, 0, stream>>>(mlp, eps, perm, z, out_mu, out_lv);
  // dec0: [Bp,128] @ Wd0[512][128] -> d0, relu
  gemm_kernel<0, true, false, false><<<dim3(TCAP, H1_ / BN), 256, 0, stream>>>(
      z, Wd0, b_dec0, d0, meta, perm, LAT_, H1_, 0);
  // dec1: [Bp,512] @ Wd1[c][1024][512] -> d1, relu
  gemm_kernel<0, true, true, true><<<dim3(TCAP, H0_ / BN), 256, 0, stream>>>(
      d0, Wd1, b_dec1, d1, meta, perm, H1_, H0_, 0);
  // out: [Bp,1024] @ Wout[2048][1024] -> scatter fp32 recon
  gemm_kernel<2, false, false, false><<<dim3(TCAP, DIN / BN), 256, 0, stream>>>(
      d1, Wout, b_out, out_recon, meta, perm, H0_, DIN, DIN);

  (void)in_sizes; (void)n_in; (void)out_size; (void)ws_size;
}

// Round 2
// 445.091 us; speedup vs baseline: 1.1427x; 1.1427x over previous
//
#include <hip/hip_runtime.h>

// ---------------------------------------------------------------------------
// CISSVAE forward on gfx950.
// R2: double-buffered LDS K-loop (1 barrier/step, stage overlaps compute),
//     XOR-swizzled LDS layout (conflict-free b128 fragment reads),
//     fused setup + fused weight-convert launches.
// ---------------------------------------------------------------------------

#define DEVI __device__ __forceinline__

constexpr int B_    = 8192;
constexpr int DIN   = 2048;
constexpr int H0_   = 1024;
constexpr int H1_   = 512;
constexpr int LAT_  = 128;
constexpr int NC    = 8;

constexpr int BM = 128, BN = 128, BK = 32;
constexpr int TCAP   = 72;            // sum ceil(cnt_c/128) <= 64 + 7
constexpr int BP_CAP = TCAP * BM;     // 9216 padded rows

#define MI_NTILES 8
#define MI_TILEC  16  // 72 ints: tile -> cluster

typedef __attribute__((ext_vector_type(8))) short bf16x8;
typedef __attribute__((ext_vector_type(4))) float f32x4;
typedef const __attribute__((address_space(1))) unsigned int* gas_uint_ptr;
typedef __attribute__((address_space(3))) unsigned int* las_uint_ptr;

DEVI unsigned short f2bf(float f) {      // RNE float -> bf16 bits
  union { float f; unsigned u; } a; a.f = f;
  unsigned r = a.u + 0x7fffu + ((a.u >> 16) & 1u);
  return (unsigned short)(r >> 16);
}

DEVI void gll16(const unsigned short* g, unsigned short* l) {
  __builtin_amdgcn_global_load_lds((gas_uint_ptr)g, (las_uint_ptr)l, 16, 0, 0);
}

// ---------------- workspace layout ----------------
constexpr size_t AL256(size_t x) { return (x + 255) & ~(size_t)255; }
constexpr size_t OFF_META = 0;                                       // 512 B
constexpr size_t OFF_PERM = 512;                                     // BP_CAP ints
constexpr size_t OFF_XG   = AL256(OFF_PERM + (size_t)BP_CAP * 4);    // u16 [BP_CAP][DIN]   (reused as d1)
constexpr size_t OFF_H0   = AL256(OFF_XG  + (size_t)BP_CAP * DIN * 2); // u16 [BP_CAP][H0]  (reused as d0)
constexpr size_t OFF_H1   = AL256(OFF_H0  + (size_t)BP_CAP * H0_ * 2); // u16 [BP_CAP][H1]  (reused as z)
constexpr size_t OFF_MLP  = AL256(OFF_H1  + (size_t)BP_CAP * H1_ * 2); // f32 [BP_CAP][256] mu|logvar
constexpr size_t OFF_BML  = AL256(OFF_MLP + (size_t)BP_CAP * 256 * 4); // f32 [256]
constexpr size_t OFF_WT0  = AL256(OFF_BML + 256 * 4);                  // u16 [NC][H0][DIN]
constexpr size_t OFF_WT1  = AL256(OFF_WT0 + (size_t)NC * DIN * H0_ * 2); // u16 [H1][H0]
constexpr size_t OFF_WML  = AL256(OFF_WT1 + (size_t)H0_ * H1_ * 2);      // u16 [256][H1]
constexpr size_t OFF_WD0  = AL256(OFF_WML + (size_t)256 * H1_ * 2);      // u16 [H1][LAT]
constexpr size_t OFF_WD1  = AL256(OFF_WD0 + (size_t)LAT_ * H1_ * 2);     // u16 [NC][H0][H1]
constexpr size_t OFF_WOUT = AL256(OFF_WD1 + (size_t)NC * H1_ * H0_ * 2); // u16 [DIN][H0]

// ---------------- setup (one block) ----------------
__global__ void setup_all(const int* __restrict__ labels, int* __restrict__ meta,
                          int* __restrict__ perm, const float* __restrict__ b_mu,
                          const float* __restrict__ b_lv, float* __restrict__ b_ml) {
  __shared__ int cnt[NC], base[NC];
  int t = threadIdx.x;
  if (t < NC) cnt[t] = 0;
  if (t < 256) b_ml[t] = (t < 128) ? b_mu[t] : b_lv[t - 128];
  __syncthreads();
  for (int i = t; i < B_; i += 1024) atomicAdd(&cnt[labels[i]], 1);
  for (int i = t; i < BP_CAP; i += 1024) perm[i] = -1;
  __syncthreads();
  if (t == 0) {
    int off = 0, nt = 0;
    for (int c = 0; c < NC; ++c) {
      base[c] = off;
      int k = (cnt[c] + BM - 1) >> 7;
      for (int j = 0; j < k; ++j) meta[MI_TILEC + nt + j] = c;
      nt += k;
      off += k << 7;
    }
    meta[MI_NTILES] = nt;
  }
  __syncthreads();
  if (t < NC) cnt[t] = base[t];        // reuse as cursors
  __syncthreads();
  for (int i = t; i < B_; i += 1024) {
    int pos = atomicAdd(&cnt[labels[i]], 1);
    perm[pos] = i;
  }
}

// ---------------- fused weight conversion: fp32 [nb][K][N] -> bf16 [nb][N][K]
struct SegDesc { const float* src; unsigned short* dst; int K, N, nb, tstart; };
struct SegTable { SegDesc s[7]; };

__global__ void convert_all(SegTable t) {
  __shared__ float tl[32][33];
  int tile = blockIdx.x;
  int si = 0;
#pragma unroll
  for (int i = 1; i < 7; ++i) si += (tile >= t.s[i].tstart) ? 1 : 0;
  const SegDesc sd = t.s[si];
  int local = tile - sd.tstart;
  int tpb = (sd.K >> 5) * (sd.N >> 5);
  int b = local / tpb, rem = local - b * tpb;
  int tk = rem / (sd.N >> 5), tn = rem - tk * (sd.N >> 5);
  const float* s = sd.src + (size_t)b * sd.K * sd.N;
  unsigned short* d = sd.dst + (size_t)b * sd.K * sd.N;
  int n0 = tn * 32, k0 = tk * 32;
  for (int i = threadIdx.y; i < 32; i += 8)
    tl[i][threadIdx.x] = s[(size_t)(k0 + i) * sd.N + n0 + threadIdx.x];
  __syncthreads();
  for (int i = threadIdx.y; i < 32; i += 8)
    d[(size_t)(n0 + i) * sd.K + k0 + threadIdx.x] = f2bf(tl[threadIdx.x][i]);
}

// gather + fp32->bf16 rows of x into permuted layout (zeros for padding rows)
__global__ void gather_x_kernel(const float* __restrict__ x, const int* __restrict__ perm,
                                unsigned short* __restrict__ xg) {
  int p = blockIdx.x;
  int c4 = blockIdx.y * 256 + threadIdx.x;   // 0..511 float4 per row
  int src = perm[p];
  float4 v = make_float4(0.f, 0.f, 0.f, 0.f);
  if (src >= 0) v = ((const float4*)(x + (size_t)src * DIN))[c4];
  ushort4 o;
  o.x = f2bf(v.x); o.y = f2bf(v.y); o.z = f2bf(v.z); o.w = f2bf(v.w);
  ((ushort4*)(xg + (size_t)p * DIN))[c4] = o;
}

// z = mu + eps*exp(0.5*logvar); scatter mu/logvar to output
__global__ void z_kernel(const float* __restrict__ mlp, const float* __restrict__ eps,
                         const int* __restrict__ perm, unsigned short* __restrict__ z,
                         float* __restrict__ out_mu, float* __restrict__ out_lv) {
  int p = blockIdx.x, j = threadIdx.x;
  int src = perm[p];
  float zz = 0.f;
  if (src >= 0) {
    float m = mlp[(size_t)p * 256 + j];
    float l = mlp[(size_t)p * 256 + 128 + j];
    zz = m + eps[(size_t)src * LAT_ + j] * expf(0.5f * l);
    out_mu[(size_t)src * LAT_ + j] = m;
    out_lv[(size_t)src * LAT_ + j] = l;
  }
  z[(size_t)p * LAT_ + j] = f2bf(zz);
}

// ---------------- GEMM: dbuf + swizzled LDS ----------------
// C[M,N] = A[M,K] @ Bt[N,K]^T. LDS slot for (row r, 16B-chunk c) is
// r*4 + (c ^ ((r>>1)&3)): each 8-lane phase of a b128 frag read covers all
// 32 banks once (conflict-free); staged by permuting each lane's SOURCE chunk.
template <int OUT_MODE, bool RELU, bool PCW, bool PCB>
__global__ __launch_bounds__(256, 2)
void gemm_kernel(const unsigned short* __restrict__ A,
                 const unsigned short* __restrict__ Bt,
                 const float* __restrict__ bias,
                 void* __restrict__ Cout,
                 const int* __restrict__ meta,
                 const int* __restrict__ perm,
                 int K, int N, int ldc) {
  const int tm = blockIdx.x;
  if (tm >= meta[MI_NTILES]) return;
  const int tn = blockIdx.y;

  int cluster = 0;
  if (PCW || PCB) cluster = meta[MI_TILEC + tm];
  const unsigned short* Bp = Bt + (PCW ? (size_t)cluster * (size_t)N * K : 0);
  const float* bb = bias + (PCB ? (size_t)cluster * N : 0);

  __shared__ alignas(16) unsigned short As[2][BM * BK];
  __shared__ alignas(16) unsigned short Bs[2][BN * BK];

  const int tid  = threadIdx.x;
  const int w    = tid >> 6, lane = tid & 63;
  const int fr   = lane & 15, quad = lane >> 4;
  const int wm   = (w >> 1) * 64, wn = (w & 1) * 64;

  // staging: slot s covers LDS bytes [s*16, s*16+16); global chunk = swizzled
  const int s0 = (w * 2 + 0) * 64 + lane;
  const int s1 = (w * 2 + 1) * 64 + lane;
  const int r0 = s0 >> 2, r1 = s1 >> 2;
  const int c0 = (s0 & 3) ^ ((r0 >> 1) & 3);
  const int c1 = (s1 & 3) ^ ((r1 >> 1) & 3);
  const size_t aoff0 = (size_t)(tm * BM + r0) * K + c0 * 8;
  const size_t aoff1 = (size_t)(tm * BM + r1) * K + c1 * 8;
  const size_t boff0 = (size_t)(tn * BN + r0) * K + c0 * 8;
  const size_t boff1 = (size_t)(tn * BN + r1) * K + c1 * 8;
  const int l0 = s0 * 8, l1 = s1 * 8;  // element offsets

  // fragment read offsets (elements): row R, chunk quad -> swizzled slot
  int aro[4], bro[4];
#pragma unroll
  for (int i = 0; i < 4; ++i) {
    int R = wm + i * 16 + fr;
    aro[i] = (R * 4 + (quad ^ ((R >> 1) & 3))) * 8;
    R = wn + i * 16 + fr;
    bro[i] = (R * 4 + (quad ^ ((R >> 1) & 3))) * 8;
  }

  f32x4 acc[4][4] = {};

  // prologue: stage tile 0 into buf 0
  gll16(A  + aoff0, &As[0][l0]);
  gll16(A  + aoff1, &As[0][l1]);
  gll16(Bp + boff0, &Bs[0][l0]);
  gll16(Bp + boff1, &Bs[0][l1]);

  int cur = 0;
  for (int k0 = BK; k0 < K; k0 += BK) {
    __syncthreads();                 // stage(cur) drained; prev reads done
    const int nxt = cur ^ 1;
    gll16(A  + aoff0 + k0, &As[nxt][l0]);   // overlaps compute below
    gll16(A  + aoff1 + k0, &As[nxt][l1]);
    gll16(Bp + boff0 + k0, &Bs[nxt][l0]);
    gll16(Bp + boff1 + k0, &Bs[nxt][l1]);

    bf16x8 af[4], bfr[4];
#pragma unroll
    for (int i = 0; i < 4; ++i) af[i]  = *(const bf16x8*)&As[cur][aro[i]];
#pragma unroll
    for (int i = 0; i < 4; ++i) bfr[i] = *(const bf16x8*)&Bs[cur][bro[i]];
#pragma unroll
    for (int mi = 0; mi < 4; ++mi)
#pragma unroll
      for (int ni = 0; ni < 4; ++ni)
        acc[mi][ni] = __builtin_amdgcn_mfma_f32_16x16x32_bf16(af[mi], bfr[ni], acc[mi][ni], 0, 0, 0);
    cur = nxt;
  }
  __syncthreads();                   // last stage drained
  {
    bf16x8 af[4], bfr[4];
#pragma unroll
    for (int i = 0; i < 4; ++i) af[i]  = *(const bf16x8*)&As[cur][aro[i]];
#pragma unroll
    for (int i = 0; i < 4; ++i) bfr[i] = *(const bf16x8*)&Bs[cur][bro[i]];
#pragma unroll
    for (int mi = 0; mi < 4; ++mi)
#pragma unroll
      for (int ni = 0; ni < 4; ++ni)
        acc[mi][ni] = __builtin_amdgcn_mfma_f32_16x16x32_bf16(af[mi], bfr[ni], acc[mi][ni], 0, 0, 0);
  }

  // epilogue: D row = wm + mi*16 + quad*4 + r (M), col = wn + ni*16 + fr (N)
  float bv[4];
#pragma unroll
  for (int ni = 0; ni < 4; ++ni) bv[ni] = bb[tn * BN + wn + ni * 16 + fr];

#pragma unroll
  for (int mi = 0; mi < 4; ++mi) {
#pragma unroll
    for (int r = 0; r < 4; ++r) {
      int m = tm * BM + wm + mi * 16 + quad * 4 + r;
      int orow = m;
      if (OUT_MODE == 2) orow = perm[m];
#pragma unroll
      for (int ni = 0; ni < 4; ++ni) {
        int n = tn * BN + wn + ni * 16 + fr;
        float v = acc[mi][ni][r] + bv[ni];
        if (RELU) v = fmaxf(v, 0.f);
        if (OUT_MODE == 0) {
          ((unsigned short*)Cout)[(size_t)m * N + n] = f2bf(v);
        } else if (OUT_MODE == 1) {
          ((float*)Cout)[(size_t)m * N + n] = v;
        } else {
          if (orow >= 0) ((float*)Cout)[(size_t)orow * ldc + n] = v;
        }
      }
    }
  }
}

// ---------------- launch ----------------
extern "C" void kernel_launch(void* const* d_in, const int* in_sizes, int n_in,
                              void* d_out, int out_size, void* d_ws, size_t ws_size,
                              hipStream_t stream) {
  const float* x        = (const float*)d_in[0];
  const int*   labels   = (const int*)d_in[1];
  const float* eps      = (const float*)d_in[2];
  const float* W_enc0   = (const float*)d_in[3];
  const float* b_enc0   = (const float*)d_in[4];
  const float* W_enc1   = (const float*)d_in[5];
  const float* b_enc1   = (const float*)d_in[6];
  const float* W_mu     = (const float*)d_in[7];
  const float* b_mu     = (const float*)d_in[8];
  const float* W_logvar = (const float*)d_in[9];
  const float* b_logvar = (const float*)d_in[10];
  const float* W_dec0   = (const float*)d_in[11];
  const float* b_dec0   = (const float*)d_in[12];
  const float* W_dec1   = (const float*)d_in[13];
  const float* b_dec1   = (const float*)d_in[14];
  const float* W_out    = (const float*)d_in[15];
  const float* b_out    = (const float*)d_in[16];

  float* out_recon = (float*)d_out;
  float* out_mu    = out_recon + (size_t)B_ * DIN;
  float* out_lv    = out_mu + (size_t)B_ * LAT_;

  char* ws = (char*)d_ws;
  int* meta            = (int*)(ws + OFF_META);
  int* perm            = (int*)(ws + OFF_PERM);
  unsigned short* xg   = (unsigned short*)(ws + OFF_XG);
  unsigned short* h0   = (unsigned short*)(ws + OFF_H0);
  unsigned short* h1   = (unsigned short*)(ws + OFF_H1);
  float* mlp           = (float*)(ws + OFF_MLP);
  float* b_ml          = (float*)(ws + OFF_BML);
  unsigned short* Wt0  = (unsigned short*)(ws + OFF_WT0);
  unsigned short* Wt1  = (unsigned short*)(ws + OFF_WT1);
  unsigned short* Wml  = (unsigned short*)(ws + OFF_WML);
  unsigned short* Wd0  = (unsigned short*)(ws + OFF_WD0);
  unsigned short* Wd1  = (unsigned short*)(ws + OFF_WD1);
  unsigned short* Wout = (unsigned short*)(ws + OFF_WOUT);
  // buffer reuse (lifetimes disjoint):
  unsigned short* d1 = xg;   // [BP_CAP][H0]
  unsigned short* d0 = h0;   // [BP_CAP][H1]
  unsigned short* z  = h1;   // [BP_CAP][LAT]

  // fused conversion table
  SegTable st;
  int ts = 0;
  auto seg = [&](int i, const float* s, unsigned short* d, int K, int N, int nb) {
    st.s[i] = SegDesc{s, d, K, N, nb, ts};
    ts += (K / 32) * (N / 32) * nb;
  };
  seg(0, W_enc0,   Wt0,                      DIN,  H0_,  NC);
  seg(1, W_enc1,   Wt1,                      H0_,  H1_,  1);
  seg(2, W_mu,     Wml,                      H1_,  LAT_, 1);
  seg(3, W_logvar, Wml + (size_t)LAT_ * H1_, H1_,  LAT_, 1);
  seg(4, W_dec0,   Wd0,                      LAT_, H1_,  1);
  seg(5, W_dec1,   Wd1,                      H1_,  H0_,  NC);
  seg(6, W_out,    Wout,                     H0_,  DIN,  1);

  setup_all<<<1, 1024, 0, stream>>>(labels, meta, perm, b_mu, b_logvar, b_ml);
  convert_all<<<ts, dim3(32, 8), 0, stream>>>(st);
  gather_x_kernel<<<dim3(BP_CAP, DIN / (256 * 4)), 256, 0, stream>>>(x, perm, xg);

  // enc0: [Bp,2048] @ Wt0[c][1024][2048] -> h0, relu
  gemm_kernel<0, true, true, true><<<dim3(TCAP, H0_ / BN), 256, 0, stream>>>(
      xg, Wt0, b_enc0, h0, meta, perm, DIN, H0_, 0);
  // enc1: [Bp,1024] @ Wt1[512][1024] -> h1, relu
  gemm_kernel<0, true, false, false><<<dim3(TCAP, H1_ / BN), 256, 0, stream>>>(
      h0, Wt1, b_enc1, h1, meta, perm, H0_, H1_, 0);
  // mu|logvar: [Bp,512] @ Wml[256][512] -> mlp (fp32)
  gemm_kernel<1, false, false, false><<<dim3(TCAP, 256 / BN), 256, 0, stream>>>(
      h1, Wml, b_ml, mlp, meta, perm, H1_, 256, 0);
  // reparameterize + scatter mu/logvar
  z_kernel<<<BP_CAP, 128, 0, stream>>>(mlp, eps, perm, z, out_mu, out_lv);
  // dec0: [Bp,128] @ Wd0[512][128] -> d0, relu
  gemm_kernel<0, true, false, false><<<dim3(TCAP, H1_ / BN), 256, 0, stream>>>(
      z, Wd0, b_dec0, d0, meta, perm, LAT_, H1_, 0);
  // dec1: [Bp,512] @ Wd1[c][1024][512] -> d1, relu
  gemm_kernel<0, true, true, true><<<dim3(TCAP, H0_ / BN), 256, 0, stream>>>(
      d0, Wd1, b_dec1, d1, meta, perm, H1_, H0_, 0);
  // out: [Bp,1024] @ Wout[2048][1024] -> scatter fp32 recon
  gemm_kernel<2, false, false, false><<<dim3(TCAP, DIN / BN), 256, 0, stream>>>(
      d1, Wout, b_out, out_recon, meta, perm, H0_, DIN, DIN);

  (void)in_sizes; (void)n_in; (void)out_size; (void)ws_size;
}

// Round 3
// 434.681 us; speedup vs baseline: 1.1700x; 1.0239x over previous
//
#include <hip/hip_runtime.h>

// ---------------------------------------------------------------------------
// CISSVAE forward on gfx950.
// R3: register-staged GEMM pipeline with asm barrier (s_waitcnt lgkmcnt(0)
//     only — global loads stay in flight across the barrier, killing the
//     ~900-cyc/iter vmcnt(0) drain that bound R1/R2), supertile grid swizzle
//     for L2 locality, coalesced weight-convert writes.
// ---------------------------------------------------------------------------

#define DEVI __device__ __forceinline__

constexpr int B_    = 8192;
constexpr int DIN   = 2048;
constexpr int H0_   = 1024;
constexpr int H1_   = 512;
constexpr int LAT_  = 128;
constexpr int NC    = 8;

constexpr int BM = 128, BN = 128, BK = 32;
constexpr int TCAP   = 72;            // sum ceil(cnt_c/128) <= 64 + 7; divisible by 8
constexpr int BP_CAP = TCAP * BM;     // 9216 padded rows

#define MI_NTILES 8
#define MI_TILEC  16  // 72 ints: tile -> cluster

typedef __attribute__((ext_vector_type(8))) short bf16x8;
typedef __attribute__((ext_vector_type(4))) float f32x4;

// barrier that does NOT drain vmcnt: LDS ops only.
#define LDS_BARRIER() asm volatile("s_waitcnt lgkmcnt(0)\n\ts_barrier" ::: "memory")

DEVI unsigned short f2bf(float f) {      // RNE float -> bf16 bits
  union { float f; unsigned u; } a; a.f = f;
  unsigned r = a.u + 0x7fffu + ((a.u >> 16) & 1u);
  return (unsigned short)(r >> 16);
}

// ---------------- workspace layout ----------------
constexpr size_t AL256(size_t x) { return (x + 255) & ~(size_t)255; }
constexpr size_t OFF_META = 0;                                       // 512 B
constexpr size_t OFF_PERM = 512;                                     // BP_CAP ints
constexpr size_t OFF_XG   = AL256(OFF_PERM + (size_t)BP_CAP * 4);    // u16 [BP_CAP][DIN]   (reused as d1)
constexpr size_t OFF_H0   = AL256(OFF_XG  + (size_t)BP_CAP * DIN * 2); // u16 [BP_CAP][H0]  (reused as d0)
constexpr size_t OFF_H1   = AL256(OFF_H0  + (size_t)BP_CAP * H0_ * 2); // u16 [BP_CAP][H1]  (reused as z)
constexpr size_t OFF_MLP  = AL256(OFF_H1  + (size_t)BP_CAP * H1_ * 2); // f32 [BP_CAP][256] mu|logvar
constexpr size_t OFF_BML  = AL256(OFF_MLP + (size_t)BP_CAP * 256 * 4); // f32 [256]
constexpr size_t OFF_WT0  = AL256(OFF_BML + 256 * 4);                  // u16 [NC][H0][DIN]
constexpr size_t OFF_WT1  = AL256(OFF_WT0 + (size_t)NC * DIN * H0_ * 2); // u16 [H1][H0]
constexpr size_t OFF_WML  = AL256(OFF_WT1 + (size_t)H0_ * H1_ * 2);      // u16 [256][H1]
constexpr size_t OFF_WD0  = AL256(OFF_WML + (size_t)256 * H1_ * 2);      // u16 [H1][LAT]
constexpr size_t OFF_WD1  = AL256(OFF_WD0 + (size_t)LAT_ * H1_ * 2);     // u16 [NC][H0][H1]
constexpr size_t OFF_WOUT = AL256(OFF_WD1 + (size_t)NC * H1_ * H0_ * 2); // u16 [DIN][H0]

// ---------------- setup (one block) ----------------
__global__ void setup_all(const int* __restrict__ labels, int* __restrict__ meta,
                          int* __restrict__ perm, const float* __restrict__ b_mu,
                          const float* __restrict__ b_lv, float* __restrict__ b_ml) {
  __shared__ int cnt[NC], base[NC];
  int t = threadIdx.x;
  if (t < NC) cnt[t] = 0;
  if (t < 256) b_ml[t] = (t < 128) ? b_mu[t] : b_lv[t - 128];
  __syncthreads();
  for (int i = t; i < B_; i += 1024) atomicAdd(&cnt[labels[i]], 1);
  for (int i = t; i < BP_CAP; i += 1024) perm[i] = -1;
  __syncthreads();
  if (t == 0) {
    int off = 0, nt = 0;
    for (int c = 0; c < NC; ++c) {
      base[c] = off;
      int k = (cnt[c] + BM - 1) >> 7;
      for (int j = 0; j < k; ++j) meta[MI_TILEC + nt + j] = c;
      nt += k;
      off += k << 7;
    }
    meta[MI_NTILES] = nt;
  }
  __syncthreads();
  if (t < NC) cnt[t] = base[t];        // reuse as cursors
  __syncthreads();
  for (int i = t; i < B_; i += 1024) {
    int pos = atomicAdd(&cnt[labels[i]], 1);
    perm[pos] = i;
  }
}

// ---------------- fused weight conversion: fp32 [nb][K][N] -> bf16 [nb][N][K]
// 64(k) x 32(n) tiles; writes are int4 (8 bf16 along K): 128 B per 8 threads.
struct SegDesc { const float* src; unsigned short* dst; int K, N, nb, tstart; };
struct SegTable { SegDesc s[7]; };

__global__ void convert_all(SegTable t) {
  __shared__ float tl[64][33];
  int tile = blockIdx.x;
  int si = 0;
#pragma unroll
  for (int i = 1; i < 7; ++i) si += (tile >= t.s[i].tstart) ? 1 : 0;
  const SegDesc sd = t.s[si];
  int local = tile - sd.tstart;
  int tpb = (sd.K >> 6) * (sd.N >> 5);
  int b = local / tpb, rem = local - b * tpb;
  int tk = rem / (sd.N >> 5), tn = rem - tk * (sd.N >> 5);
  const float* s = sd.src + (size_t)b * sd.K * sd.N;
  unsigned short* d = sd.dst + (size_t)b * sd.K * sd.N;
  int n0 = tn * 32, k0 = tk * 64;
  int tx = threadIdx.x, ty = threadIdx.y;          // (32, 8)
  for (int i = ty; i < 64; i += 8)
    tl[i][tx] = s[(size_t)(k0 + i) * sd.N + n0 + tx];
  __syncthreads();
  int id = ty * 32 + tx;
  int j = id >> 3;                 // 0..31 (n within tile)
  int kk = (id & 7) * 8;           // 0..56 (k within tile)
  unsigned short v[8];
#pragma unroll
  for (int q = 0; q < 8; ++q) v[q] = f2bf(tl[kk + q][j]);
  *(int4*)&d[(size_t)(n0 + j) * sd.K + k0 + kk] = *(int4*)v;
}

// gather + fp32->bf16 rows of x into permuted layout (zeros for padding rows)
__global__ void gather_x_kernel(const float* __restrict__ x, const int* __restrict__ perm,
                                unsigned short* __restrict__ xg) {
  int p = blockIdx.x;
  int c4 = blockIdx.y * 256 + threadIdx.x;   // 0..511 float4 per row
  int src = perm[p];
  float4 v = make_float4(0.f, 0.f, 0.f, 0.f);
  if (src >= 0) v = ((const float4*)(x + (size_t)src * DIN))[c4];
  ushort4 o;
  o.x = f2bf(v.x); o.y = f2bf(v.y); o.z = f2bf(v.z); o.w = f2bf(v.w);
  ((ushort4*)(xg + (size_t)p * DIN))[c4] = o;
}

// z = mu + eps*exp(0.5*logvar); scatter mu/logvar to output
__global__ void z_kernel(const float* __restrict__ mlp, const float* __restrict__ eps,
                         const int* __restrict__ perm, unsigned short* __restrict__ z,
                         float* __restrict__ out_mu, float* __restrict__ out_lv) {
  int p = blockIdx.x, j = threadIdx.x;
  int src = perm[p];
  float zz = 0.f;
  if (src >= 0) {
    float m = mlp[(size_t)p * 256 + j];
    float l = mlp[(size_t)p * 256 + 128 + j];
    zz = m + eps[(size_t)src * LAT_ + j] * expf(0.5f * l);
    out_mu[(size_t)src * LAT_ + j] = m;
    out_lv[(size_t)src * LAT_ + j] = l;
  }
  z[(size_t)p * LAT_ + j] = f2bf(zz);
}

// ---------------- GEMM: register-staged pipeline, asm LDS-only barrier ----
// C[M,N] = A[M,K] @ Bt[N,K]^T. LDS slot for (row r, 16B-chunk c) is
// r*4 + (c ^ ((r>>1)&3)) (conflict-free b128 reads; staged by permuting each
// lane's SOURCE chunk). Global loads go to registers and stay in flight
// across the barrier; only the ds_write waits (precise vmcnt) after compute.
template <int OUT_MODE, bool RELU, bool PCW, bool PCB>
__global__ __launch_bounds__(256, 2)
void gemm_kernel(const unsigned short* __restrict__ A,
                 const unsigned short* __restrict__ Bt,
                 const float* __restrict__ bias,
                 void* __restrict__ Cout,
                 const int* __restrict__ meta,
                 const int* __restrict__ perm,
                 int K, int N, int ldc) {
  // supertile swizzle: 8 consecutive tm share each tn sweep -> L2 reuse
  const int ntn = N >> 7;
  const int sup = 8 * ntn;
  const int gid = blockIdx.x;
  const int tm  = (gid / sup) * 8 + (gid & 7);
  const int tn  = (gid % sup) >> 3;
  if (tm >= meta[MI_NTILES]) return;

  int cluster = 0;
  if (PCW || PCB) cluster = meta[MI_TILEC + tm];
  const unsigned short* Bp = Bt + (PCW ? (size_t)cluster * (size_t)N * K : 0);
  const float* bb = bias + (PCB ? (size_t)cluster * N : 0);

  __shared__ alignas(16) unsigned short As[2][BM * BK];
  __shared__ alignas(16) unsigned short Bs[2][BN * BK];

  const int tid  = threadIdx.x;
  const int w    = tid >> 6, lane = tid & 63;
  const int fr   = lane & 15, quad = lane >> 4;
  const int wm   = (w >> 1) * 64, wn = (w & 1) * 64;

  // staging slots (16B each); global source chunk is XOR-swizzled
  const int s0 = (w * 2 + 0) * 64 + lane;
  const int s1 = (w * 2 + 1) * 64 + lane;
  const int r0 = s0 >> 2, r1 = s1 >> 2;
  const int c0 = (s0 & 3) ^ ((r0 >> 1) & 3);
  const int c1 = (s1 & 3) ^ ((r1 >> 1) & 3);
  const size_t aoff0 = (size_t)(tm * BM + r0) * K + c0 * 8;
  const size_t aoff1 = (size_t)(tm * BM + r1) * K + c1 * 8;
  const size_t boff0 = (size_t)(tn * BN + r0) * K + c0 * 8;
  const size_t boff1 = (size_t)(tn * BN + r1) * K + c1 * 8;
  const int l0 = s0 * 8, l1 = s1 * 8;  // element offsets in LDS

  // fragment read offsets (elements)
  int aro[4], bro[4];
#pragma unroll
  for (int i = 0; i < 4; ++i) {
    int R = wm + i * 16 + fr;
    aro[i] = (R * 4 + (quad ^ ((R >> 1) & 3))) * 8;
    R = wn + i * 16 + fr;
    bro[i] = (R * 4 + (quad ^ ((R >> 1) & 3))) * 8;
  }

  f32x4 acc[4][4] = {};

  // prologue: tile 0 -> regs -> LDS[0]; tile 1 -> regs (in flight)
  int4 ra0 = *(const int4*)(A  + aoff0);
  int4 ra1 = *(const int4*)(A  + aoff1);
  int4 rb0 = *(const int4*)(Bp + boff0);
  int4 rb1 = *(const int4*)(Bp + boff1);
  *(int4*)&As[0][l0] = ra0;
  *(int4*)&As[0][l1] = ra1;
  *(int4*)&Bs[0][l0] = rb0;
  *(int4*)&Bs[0][l1] = rb1;
  if (K > BK) {
    ra0 = *(const int4*)(A  + aoff0 + BK);
    ra1 = *(const int4*)(A  + aoff1 + BK);
    rb0 = *(const int4*)(Bp + boff0 + BK);
    rb1 = *(const int4*)(Bp + boff1 + BK);
  }
  LDS_BARRIER();

  int cur = 0;
  for (int k0 = BK; k0 < K; k0 += BK) {
    const int nxt = cur ^ 1;
    // compute tile (k0-BK) from LDS[cur]
    bf16x8 af[4], bfr[4];
#pragma unroll
    for (int i = 0; i < 4; ++i) af[i]  = *(const bf16x8*)&As[cur][aro[i]];
#pragma unroll
    for (int i = 0; i < 4; ++i) bfr[i] = *(const bf16x8*)&Bs[cur][bro[i]];
#pragma unroll
    for (int mi = 0; mi < 4; ++mi)
#pragma unroll
      for (int ni = 0; ni < 4; ++ni)
        acc[mi][ni] = __builtin_amdgcn_mfma_f32_16x16x32_bf16(af[mi], bfr[ni], acc[mi][ni], 0, 0, 0);

    // stage tile k0 (regs, loaded last iter) into LDS[nxt]; vmcnt wait is
    // precise and sits AFTER the compute phase above.
    *(int4*)&As[nxt][l0] = ra0;
    *(int4*)&As[nxt][l1] = ra1;
    *(int4*)&Bs[nxt][l0] = rb0;
    *(int4*)&Bs[nxt][l1] = rb1;
    // issue loads for tile k0+BK (stay in flight across the barrier)
    if (k0 + BK < K) {
      ra0 = *(const int4*)(A  + aoff0 + k0 + BK);
      ra1 = *(const int4*)(A  + aoff1 + k0 + BK);
      rb0 = *(const int4*)(Bp + boff0 + k0 + BK);
      rb1 = *(const int4*)(Bp + boff1 + k0 + BK);
    }
    LDS_BARRIER();
    cur = nxt;
  }

  // final tile
  {
    bf16x8 af[4], bfr[4];
#pragma unroll
    for (int i = 0; i < 4; ++i) af[i]  = *(const bf16x8*)&As[cur][aro[i]];
#pragma unroll
    for (int i = 0; i < 4; ++i) bfr[i] = *(const bf16x8*)&Bs[cur][bro[i]];
#pragma unroll
    for (int mi = 0; mi < 4; ++mi)
#pragma unroll
      for (int ni = 0; ni < 4; ++ni)
        acc[mi][ni] = __builtin_amdgcn_mfma_f32_16x16x32_bf16(af[mi], bfr[ni], acc[mi][ni], 0, 0, 0);
  }

  // epilogue: D row = wm + mi*16 + quad*4 + r (M), col = wn + ni*16 + fr (N)
  float bv[4];
#pragma unroll
  for (int ni = 0; ni < 4; ++ni) bv[ni] = bb[tn * BN + wn + ni * 16 + fr];

#pragma unroll
  for (int mi = 0; mi < 4; ++mi) {
#pragma unroll
    for (int r = 0; r < 4; ++r) {
      int m = tm * BM + wm + mi * 16 + quad * 4 + r;
      int orow = m;
      if (OUT_MODE == 2) orow = perm[m];
#pragma unroll
      for (int ni = 0; ni < 4; ++ni) {
        int n = tn * BN + wn + ni * 16 + fr;
        float v = acc[mi][ni][r] + bv[ni];
        if (RELU) v = fmaxf(v, 0.f);
        if (OUT_MODE == 0) {
          ((unsigned short*)Cout)[(size_t)m * N + n] = f2bf(v);
        } else if (OUT_MODE == 1) {
          ((float*)Cout)[(size_t)m * N + n] = v;
        } else {
          if (orow >= 0) ((float*)Cout)[(size_t)orow * ldc + n] = v;
        }
      }
    }
  }
}

// ---------------- launch ----------------
extern "C" void kernel_launch(void* const* d_in, const int* in_sizes, int n_in,
                              void* d_out, int out_size, void* d_ws, size_t ws_size,
                              hipStream_t stream) {
  const float* x        = (const float*)d_in[0];
  const int*   labels   = (const int*)d_in[1];
  const float* eps      = (const float*)d_in[2];
  const float* W_enc0   = (const float*)d_in[3];
  const float* b_enc0   = (const float*)d_in[4];
  const float* W_enc1   = (const float*)d_in[5];
  const float* b_enc1   = (const float*)d_in[6];
  const float* W_mu     = (const float*)d_in[7];
  const float* b_mu     = (const float*)d_in[8];
  const float* W_logvar = (const float*)d_in[9];
  const float* b_logvar = (const float*)d_in[10];
  const float* W_dec0   = (const float*)d_in[11];
  const float* b_dec0   = (const float*)d_in[12];
  const float* W_dec1   = (const float*)d_in[13];
  const float* b_dec1   = (const float*)d_in[14];
  const float* W_out    = (const float*)d_in[15];
  const float* b_out    = (const float*)d_in[16];

  float* out_recon = (float*)d_out;
  float* out_mu    = out_recon + (size_t)B_ * DIN;
  float* out_lv    = out_mu + (size_t)B_ * LAT_;

  char* ws = (char*)d_ws;
  int* meta            = (int*)(ws + OFF_META);
  int* perm            = (int*)(ws + OFF_PERM);
  unsigned short* xg   = (unsigned short*)(ws + OFF_XG);
  unsigned short* h0   = (unsigned short*)(ws + OFF_H0);
  unsigned short* h1   = (unsigned short*)(ws + OFF_H1);
  float* mlp           = (float*)(ws + OFF_MLP);
  float* b_ml          = (float*)(ws + OFF_BML);
  unsigned short* Wt0  = (unsigned short*)(ws + OFF_WT0);
  unsigned short* Wt1  = (unsigned short*)(ws + OFF_WT1);
  unsigned short* Wml  = (unsigned short*)(ws + OFF_WML);
  unsigned short* Wd0  = (unsigned short*)(ws + OFF_WD0);
  unsigned short* Wd1  = (unsigned short*)(ws + OFF_WD1);
  unsigned short* Wout = (unsigned short*)(ws + OFF_WOUT);
  // buffer reuse (lifetimes disjoint):
  unsigned short* d1 = xg;   // [BP_CAP][H0]
  unsigned short* d0 = h0;   // [BP_CAP][H1]
  unsigned short* z  = h1;   // [BP_CAP][LAT]

  // fused conversion table (64k x 32n tiles)
  SegTable st;
  int ts = 0;
  auto seg = [&](int i, const float* s, unsigned short* d, int K, int N, int nb) {
    st.s[i] = SegDesc{s, d, K, N, nb, ts};
    ts += (K / 64) * (N / 32) * nb;
  };
  seg(0, W_enc0,   Wt0,                      DIN,  H0_,  NC);
  seg(1, W_enc1,   Wt1,                      H0_,  H1_,  1);
  seg(2, W_mu,     Wml,                      H1_,  LAT_, 1);
  seg(3, W_logvar, Wml + (size_t)LAT_ * H1_, H1_,  LAT_, 1);
  seg(4, W_dec0,   Wd0,                      LAT_, H1_,  1);
  seg(5, W_dec1,   Wd1,                      H1_,  H0_,  NC);
  seg(6, W_out,    Wout,                     H0_,  DIN,  1);

  setup_all<<<1, 1024, 0, stream>>>(labels, meta, perm, b_mu, b_logvar, b_ml);
  convert_all<<<ts, dim3(32, 8), 0, stream>>>(st);
  gather_x_kernel<<<dim3(BP_CAP, DIN / (256 * 4)), 256, 0, stream>>>(x, perm, xg);

  // enc0: [Bp,2048] @ Wt0[c][1024][2048] -> h0, relu
  gemm_kernel<0, true, true, true><<<TCAP * (H0_ / BN), 256, 0, stream>>>(
      xg, Wt0, b_enc0, h0, meta, perm, DIN, H0_, 0);
  // enc1: [Bp,1024] @ Wt1[512][1024] -> h1, relu
  gemm_kernel<0, true, false, false><<<TCAP * (H1_ / BN), 256, 0, stream>>>(
      h0, Wt1, b_enc1, h1, meta, perm, H0_, H1_, 0);
  // mu|logvar: [Bp,512] @ Wml[256][512] -> mlp (fp32)
  gemm_kernel<1, false, false, false><<<TCAP * (256 / BN), 256, 0, stream>>>(
      h1, Wml, b_ml, mlp, meta, perm, H1_, 256, 0);
  // reparameterize + scatter mu/logvar
  z_kernel<<<BP_CAP, 128, 0, stream>>>(mlp, eps, perm, z, out_mu, out_lv);
  // dec0: [Bp,128] @ Wd0[512][128] -> d0, relu
  gemm_kernel<0, true, false, false><<<TCAP * (H1_ / BN), 256, 0, stream>>>(
      z, Wd0, b_dec0, d0, meta, perm, LAT_, H1_, 0);
  // dec1: [Bp,512] @ Wd1[c][1024][512] -> d1, relu
  gemm_kernel<0, true, true, true><<<TCAP * (H0_ / BN), 256, 0, stream>>>(
      d0, Wd1, b_dec1, d1, meta, perm, H1_, H0_, 0);
  // out: [Bp,1024] @ Wout[2048][1024] -> scatter fp32 recon
  gemm_kernel<2, false, false, false><<<TCAP * (DIN / BN), 256, 0, stream>>>(
      d1, Wout, b_out, out_recon, meta, perm, H0_, DIN, DIN);

  (void)in_sizes; (void)n_in; (void)out_size; (void)ws_size;
}